// Round 1
// baseline (280.823 us; speedup 1.0000x reference)
//
#include <hip/hip_runtime.h>
#include <hip/hip_bf16.h>
#include <stdint.h>

// Problem: N=8192 tokens, D=128, HEADS=16, dh=2048.
// Pipeline: prep weights -> q3/k3/v3 projections (bf16, MFMA-layouts in ws)
//           -> per-token attention (S^T + wave-local softmax + PV)
//           -> output projection (f32 out).
//
// ws layout (needs ~98 MB):
//   [0,32M)   q3  bf16 [n][g][i][c] (g=h>>3, c=h&7)  -- later overwritten by out3 [n][f]
//   [32,64M)  k3  bf16 same layout
//   [64,96M)  v3  bf16 [n][h][j]
//   [96M..)   WqT/WkT/WvT bf16 [2048][128], WoT bf16 [128][2048]

#define NTOK 8192
#define DDIM 128
#define DH   2048

typedef float   f32x16 __attribute__((ext_vector_type(16)));
typedef __bf16  bf16x8 __attribute__((ext_vector_type(8)));
typedef uint32_t u32x4 __attribute__((ext_vector_type(4)));

static __device__ __forceinline__ uint32_t cvt_pk_bf16(float lo, float hi) {
  uint32_t r;
  asm("v_cvt_pk_bf16_f32 %0, %1, %2" : "=v"(r) : "v"(lo), "v"(hi));
  return r;
}
// C/D row mapping for mfma_f32_32x32x16: row = (r&3) + 8*(r>>2) + 4*hi, col = lane&31
static __device__ __forceinline__ int crow4(int r, int hi) {
  return (r & 3) + 8 * (r >> 2) + 4 * hi;
}

// ---------------- Kernel 0: weight prep ----------------
// Wq/Wk/Wv f32 [128][2048] -> WT bf16 [2048 col][128 k]
// Wo f32 [2048][128] -> WoT bf16 [128 col][2048 k]
__global__ __launch_bounds__(256) void prep_weights(
    const float* __restrict__ Wq, const float* __restrict__ Wk,
    const float* __restrict__ Wv, const float* __restrict__ Wo,
    uint16_t* __restrict__ WqT, uint16_t* __restrict__ WkT,
    uint16_t* __restrict__ WvT, uint16_t* __restrict__ WoT) {
  const int t = threadIdx.x, bx = blockIdx.x, z = blockIdx.y;
  if (z < 3) {
    const float* W = (z == 0) ? Wq : (z == 1) ? Wk : Wv;
    uint16_t* WT = (z == 0) ? WqT : (z == 1) ? WkT : WvT;
    const int col = bx * 256 + t;
    for (int kc = 0; kc < 16; ++kc) {
      u32x4 wv;
      #pragma unroll
      for (int p = 0; p < 4; ++p) {
        float f0 = W[(size_t)(kc * 8 + 2 * p) * DH + col];
        float f1 = W[(size_t)(kc * 8 + 2 * p + 1) * DH + col];
        wv[p] = cvt_pk_bf16(f0, f1);
      }
      *(u32x4*)(WT + (size_t)col * 128 + kc * 8) = wv;
    }
  } else {
    const int col = t & 127, ksub = t >> 7;
    const int kbase = bx * 256 + ksub * 128;
    for (int kc = 0; kc < 16; ++kc) {
      const int k0 = kbase + kc * 8;
      u32x4 wv;
      #pragma unroll
      for (int p = 0; p < 4; ++p) {
        float f0 = Wo[(size_t)(k0 + 2 * p) * DDIM + col];
        float f1 = Wo[(size_t)(k0 + 2 * p + 1) * DDIM + col];
        wv[p] = cvt_pk_bf16(f0, f1);
      }
      *(u32x4*)(WoT + (size_t)col * DH + k0) = wv;
    }
  }
}

// ---------------- Kernel 1: Q/K/V projections ----------------
// C = A[8192x128] @ W[128x2048] + b, stored bf16 in attention layouts.
// q3/k3: u16 idx = n*2048 + ((f>>3)&1)*1024 + (f>>4)*8 + (f&7)   (f = i*16+h)
// v3   : u16 idx = n*2048 + (f&15)*128 + (f>>4)                  ([h][j])
__global__ __launch_bounds__(256) void proj_kernel(
    const float* __restrict__ q, const float* __restrict__ kin,
    const float* __restrict__ v,
    const uint16_t* __restrict__ WqT, const uint16_t* __restrict__ WkT,
    const uint16_t* __restrict__ WvT,
    const float* __restrict__ bq, const float* __restrict__ bk,
    const float* __restrict__ bv,
    uint16_t* __restrict__ q3, uint16_t* __restrict__ k3,
    uint16_t* __restrict__ v3) {
  const int z = blockIdx.z;
  const float* A = (z == 0) ? q : (z == 1) ? kin : v;
  const uint16_t* WT = (z == 0) ? WqT : (z == 1) ? WkT : WvT;
  const float* bias = (z == 0) ? bq : (z == 1) ? bk : bv;
  uint16_t* dst = (z == 0) ? q3 : (z == 1) ? k3 : v3;

  const int w = threadIdx.x >> 6;
  const int l = threadIdx.x & 63;
  const int il = l & 31, hi = l >> 5;
  const int rowbase = blockIdx.x * 32;
  const int colbase = blockIdx.y * 512 + w * 128;

  f32x16 acc0 = {}, acc1 = {}, acc2 = {}, acc3 = {};
  #pragma unroll
  for (int ks = 0; ks < 8; ++ks) {
    const int kk = ks * 16 + hi * 8;
    const float* ap = A + (size_t)(rowbase + il) * DDIM + kk;
    float4 a0 = *(const float4*)ap;
    float4 a1 = *(const float4*)(ap + 4);
    u32x4 av = { cvt_pk_bf16(a0.x, a0.y), cvt_pk_bf16(a0.z, a0.w),
                 cvt_pk_bf16(a1.x, a1.y), cvt_pk_bf16(a1.z, a1.w) };
    bf16x8 af = __builtin_bit_cast(bf16x8, av);
    bf16x8 b0 = *(const bf16x8*)(WT + (size_t)(colbase + 0 * 32 + il) * 128 + kk);
    bf16x8 b1 = *(const bf16x8*)(WT + (size_t)(colbase + 1 * 32 + il) * 128 + kk);
    bf16x8 b2 = *(const bf16x8*)(WT + (size_t)(colbase + 2 * 32 + il) * 128 + kk);
    bf16x8 b3 = *(const bf16x8*)(WT + (size_t)(colbase + 3 * 32 + il) * 128 + kk);
    acc0 = __builtin_amdgcn_mfma_f32_32x32x16_bf16(af, b0, acc0, 0, 0, 0);
    acc1 = __builtin_amdgcn_mfma_f32_32x32x16_bf16(af, b1, acc1, 0, 0, 0);
    acc2 = __builtin_amdgcn_mfma_f32_32x32x16_bf16(af, b2, acc2, 0, 0, 0);
    acc3 = __builtin_amdgcn_mfma_f32_32x32x16_bf16(af, b3, acc3, 0, 0, 0);
  }
  const bool vlayout = (z == 2);
  #pragma unroll
  for (int nt = 0; nt < 4; ++nt) {
    const f32x16 acc = (nt == 0) ? acc0 : (nt == 1) ? acc1 : (nt == 2) ? acc2 : acc3;
    const int col = colbase + nt * 32 + il;
    const float bval = bias[col];
    size_t base;
    if (!vlayout) base = (size_t)((col >> 3) & 1) * 1024 + (size_t)(col >> 4) * 8 + (col & 7);
    else          base = (size_t)(col & 15) * 128 + (col >> 4);
    #pragma unroll
    for (int r = 0; r < 16; ++r) {
      const int n = rowbase + crow4(r, hi);
      float fv = acc[r] + bval;
      __hip_bfloat16 h = __float2bfloat16(fv);
      dst[(size_t)n * 2048 + base] = __builtin_bit_cast(uint16_t, h);
    }
  }
}

// ---------------- Kernel 2: per-token attention ----------------
// One WG (4 waves) per token. S^T = k3 · q3^T (so softmax over i is a
// wave-local row reduction), fold 1/denom into P, P->bf16 via cvt_pk +
// permlane32_swap, PV with per-wave j-slab + LDS 4-way reduce.
// out3 (bf16 [n][f], f=i*16+h) overwrites the q3 region.
__global__ __launch_bounds__(256) void attn_kernel(
    const uint16_t* q3, const uint16_t* __restrict__ k3,
    const uint16_t* __restrict__ v3, uint16_t* out3) {
  __shared__ float part[4][128][16];
  const int n = blockIdx.x;
  const int w = threadIdx.x >> 6;
  const int l = threadIdx.x & 63;
  const int il = l & 31, hi = l >> 5;
  const uint16_t* qb = q3 + (size_t)n * 2048;
  const uint16_t* kb = k3 + (size_t)n * 2048;
  const uint16_t* vb = v3 + (size_t)n * 2048;

  // A-frag: k3 rows j = 32w+il, k = h = hi*8..+7
  bf16x8 af = *(const bf16x8*)(kb + hi * 1024 + (size_t)(w * 32 + il) * 8);
  f32x16 d0 = {}, d1 = {}, d2 = {}, d3 = {};
  {
    bf16x8 bq0 = *(const bf16x8*)(qb + hi * 1024 + (size_t)(0 * 32 + il) * 8);
    bf16x8 bq1 = *(const bf16x8*)(qb + hi * 1024 + (size_t)(1 * 32 + il) * 8);
    bf16x8 bq2 = *(const bf16x8*)(qb + hi * 1024 + (size_t)(2 * 32 + il) * 8);
    bf16x8 bq3 = *(const bf16x8*)(qb + hi * 1024 + (size_t)(3 * 32 + il) * 8);
    d0 = __builtin_amdgcn_mfma_f32_32x32x16_bf16(af, bq0, d0, 0, 0, 0);
    d1 = __builtin_amdgcn_mfma_f32_32x32x16_bf16(af, bq1, d1, 0, 0, 0);
    d2 = __builtin_amdgcn_mfma_f32_32x32x16_bf16(af, bq2, d2, 0, 0, 0);
    d3 = __builtin_amdgcn_mfma_f32_32x32x16_bf16(af, bq3, d3, 0, 0, 0);
  }
  // softmax over i (cols): per row (reg,hi): sum over 4 tiles + 32-lane butterfly
  const float CEXP = 1.4426950408889634f * 0.08838834764831845f; // log2(e)/sqrt(128)
  #pragma unroll
  for (int r = 0; r < 16; ++r) {
    float e0 = exp2f(d0[r] * CEXP), e1 = exp2f(d1[r] * CEXP);
    float e2 = exp2f(d2[r] * CEXP), e3 = exp2f(d3[r] * CEXP);
    float s = (e0 + e1) + (e2 + e3);
    s += __shfl_xor(s, 1);  s += __shfl_xor(s, 2);  s += __shfl_xor(s, 4);
    s += __shfl_xor(s, 8);  s += __shfl_xor(s, 16);
    const float rs = __builtin_amdgcn_rcpf(s);
    d0[r] = e0 * rs; d1[r] = e1 * rs; d2[r] = e2 * rs; d3[r] = e3 * rs;
  }
  // V B-frags: col h = il (h<16 valid), k j = 32w + 16ks + 8hi + c
  bf16x8 vf0 = *(const bf16x8*)(vb + (size_t)(il & 15) * 128 + (w * 32 + hi * 8));
  bf16x8 vf1 = *(const bf16x8*)(vb + (size_t)(il & 15) * 128 + (w * 32 + 16 + hi * 8));

  f32x16 o[4];
  #pragma unroll
  for (int mi = 0; mi < 4; ++mi) {
    const f32x16 p = (mi == 0) ? d0 : (mi == 1) ? d1 : (mi == 2) ? d2 : d3;
    uint32_t pk0 = cvt_pk_bf16(p[0],  p[1]),  pk1 = cvt_pk_bf16(p[2],  p[3]);
    uint32_t pk2 = cvt_pk_bf16(p[4],  p[5]),  pk3 = cvt_pk_bf16(p[6],  p[7]);
    uint32_t pk4 = cvt_pk_bf16(p[8],  p[9]),  pk5 = cvt_pk_bf16(p[10], p[11]);
    uint32_t pk6 = cvt_pk_bf16(p[12], p[13]), pk7 = cvt_pk_bf16(p[14], p[15]);
    // swap(x,y): r[0] = [x_lo | y_lo], r[1] = [x_hi | y_hi]
    auto sA = __builtin_amdgcn_permlane32_swap(pk0, pk2, false, false); // W0, W2
    auto sB = __builtin_amdgcn_permlane32_swap(pk1, pk3, false, false); // W1, W3
    auto sC = __builtin_amdgcn_permlane32_swap(pk4, pk6, false, false); // W0',W2'
    auto sD = __builtin_amdgcn_permlane32_swap(pk5, pk7, false, false); // W1',W3'
    u32x4 fw0 = { sA[0], sB[0], sA[1], sB[1] };
    u32x4 fw1 = { sC[0], sD[0], sC[1], sD[1] };
    f32x16 oz = {};
    oz    = __builtin_amdgcn_mfma_f32_32x32x16_bf16(__builtin_bit_cast(bf16x8, fw0), vf0, oz, 0, 0, 0);
    o[mi] = __builtin_amdgcn_mfma_f32_32x32x16_bf16(__builtin_bit_cast(bf16x8, fw1), vf1, oz, 0, 0, 0);
  }
  if (il < 16) {
    #pragma unroll
    for (int mi = 0; mi < 4; ++mi) {
      #pragma unroll
      for (int r = 0; r < 16; ++r)
        part[w][mi * 32 + crow4(r, hi)][il] = o[mi][r];
    }
  }
  __syncthreads();
  const int t = threadIdx.x;
  const int i0 = t >> 1, h0 = (t & 1) * 8;
  float sv[8];
  #pragma unroll
  for (int e = 0; e < 8; ++e)
    sv[e] = part[0][i0][h0 + e] + part[1][i0][h0 + e] +
            part[2][i0][h0 + e] + part[3][i0][h0 + e];
  u32x4 ov = { cvt_pk_bf16(sv[0], sv[1]), cvt_pk_bf16(sv[2], sv[3]),
               cvt_pk_bf16(sv[4], sv[5]), cvt_pk_bf16(sv[6], sv[7]) };
  *(u32x4*)(out3 + (size_t)n * 2048 + t * 8) = ov;
}

// ---------------- Kernel 3: output projection ----------------
// out = out3[8192x2048](bf16) @ Wo + bo, f32 out. K-split 2 per block.
__global__ __launch_bounds__(512) void outproj_kernel(
    const uint16_t* __restrict__ out3, const uint16_t* __restrict__ WoT,
    const float* __restrict__ bo, float* __restrict__ out) {
  __shared__ float part[4][32][32];
  const int w = threadIdx.x >> 6;
  const int l = threadIdx.x & 63;
  const int il = l & 31, hi = l >> 5;
  const int nt = w >> 1, ksv = w & 1;
  const int rowbase = blockIdx.x * 32;
  f32x16 acc = {};
  #pragma unroll 4
  for (int kb = 0; kb < 64; ++kb) {
    const int kk = ksv * 1024 + kb * 16 + hi * 8;
    bf16x8 afr = *(const bf16x8*)(out3 + (size_t)(rowbase + il) * DH + kk);
    bf16x8 bfr = *(const bf16x8*)(WoT + (size_t)(nt * 32 + il) * DH + kk);
    acc = __builtin_amdgcn_mfma_f32_32x32x16_bf16(afr, bfr, acc, 0, 0, 0);
  }
  if (ksv == 1) {
    #pragma unroll
    for (int r = 0; r < 16; ++r) part[nt][crow4(r, hi)][il] = acc[r];
  }
  __syncthreads();
  if (ksv == 0) {
    const int col = nt * 32 + il;
    const float bval = bo[col];
    #pragma unroll
    for (int r = 0; r < 16; ++r) {
      const int rr = crow4(r, hi);
      out[(size_t)(rowbase + rr) * DDIM + col] = acc[r] + part[nt][rr][il] + bval;
    }
  }
}

extern "C" void kernel_launch(void* const* d_in, const int* in_sizes, int n_in,
                              void* d_out, int out_size, void* d_ws, size_t ws_size,
                              hipStream_t stream) {
  (void)in_sizes; (void)n_in; (void)out_size; (void)ws_size;
  const float* q  = (const float*)d_in[0];
  const float* k  = (const float*)d_in[1];
  const float* v  = (const float*)d_in[2];
  const float* Wq = (const float*)d_in[3];
  const float* bq = (const float*)d_in[4];
  const float* Wk = (const float*)d_in[5];
  const float* bk = (const float*)d_in[6];
  const float* Wv = (const float*)d_in[7];
  const float* bv = (const float*)d_in[8];
  const float* Wo = (const float*)d_in[9];
  const float* bo = (const float*)d_in[10];
  float* out = (float*)d_out;

  char* ws = (char*)d_ws;
  const size_t MB = 1024ull * 1024ull;
  uint16_t* q3  = (uint16_t*)(ws);             // 32MB; becomes out3
  uint16_t* k3  = (uint16_t*)(ws + 32 * MB);
  uint16_t* v3  = (uint16_t*)(ws + 64 * MB);
  uint16_t* WqT = (uint16_t*)(ws + 96 * MB);   // 512KB each
  uint16_t* WkT = WqT + (size_t)DH * 128;
  uint16_t* WvT = WkT + (size_t)DH * 128;
  uint16_t* WoT = WvT + (size_t)DH * 128;

  prep_weights<<<dim3(8, 4), 256, 0, stream>>>(Wq, Wk, Wv, Wo, WqT, WkT, WvT, WoT);
  proj_kernel<<<dim3(256, 4, 3), 256, 0, stream>>>(q, k, v, WqT, WkT, WvT,
                                                   bq, bk, bv, q3, k3, v3);
  attn_kernel<<<dim3(NTOK), 256, 0, stream>>>(q3, k3, v3, q3);
  outproj_kernel<<<dim3(256), 512, 0, stream>>>(q3, WoT, bo, out);
}

// Round 2
// 185.126 us; speedup vs baseline: 1.5169x; 1.5169x over previous
//
#include <hip/hip_runtime.h>
#include <hip/hip_bf16.h>
#include <stdint.h>

// Problem: N=8192 tokens, D=128, HEADS=16, dh=2048.
// Pipeline: prep weights -> q3/k3/v3 projections (bf16, MFMA-layouts in ws)
//           -> per-token attention (S^T + wave-local softmax + PV)
//           -> output projection (f32 out).
//
// ws layout (needs ~98 MB):
//   [0,32M)   q3  bf16 [n][g][i][c] (g=h>>3, c=h&7)  -- later overwritten by out3 [n][f]
//   [32,64M)  k3  bf16 same layout
//   [64,96M)  v3  bf16 [n][h][j]
//   [96M..)   WqT/WkT/WvT bf16 [2048][128], WoT bf16 [128][2048]

#define NTOK 8192
#define DDIM 128
#define DH   2048

typedef float   f32x16 __attribute__((ext_vector_type(16)));
typedef __bf16  bf16x8 __attribute__((ext_vector_type(8)));
typedef uint32_t u32x4 __attribute__((ext_vector_type(4)));

static __device__ __forceinline__ uint32_t cvt_pk_bf16(float lo, float hi) {
  uint32_t r;
  asm("v_cvt_pk_bf16_f32 %0, %1, %2" : "=v"(r) : "v"(lo), "v"(hi));
  return r;
}
static __device__ __forceinline__ uint16_t bf16bits(float f) {
  __hip_bfloat16 h = __float2bfloat16(f);
  return __builtin_bit_cast(uint16_t, h);
}
// C/D row mapping for mfma_f32_32x32x16: row = (r&3) + 8*(r>>2) + 4*hi, col = lane&31
static __device__ __forceinline__ int crow4(int r, int hi) {
  return (r & 3) + 8 * (r >> 2) + 4 * hi;
}

// ---------------- Kernel 0: weight prep ----------------
// Wq/Wk/Wv f32 [128][2048] -> WT bf16 [2048 col][128 k]
// Wo f32 [2048][128] -> WoT bf16 [128 col][2048 k]
__global__ __launch_bounds__(256) void prep_weights(
    const float* __restrict__ Wq, const float* __restrict__ Wk,
    const float* __restrict__ Wv, const float* __restrict__ Wo,
    uint16_t* __restrict__ WqT, uint16_t* __restrict__ WkT,
    uint16_t* __restrict__ WvT, uint16_t* __restrict__ WoT) {
  const int t = threadIdx.x, bx = blockIdx.x, z = blockIdx.y;
  if (z < 3) {
    const float* W = (z == 0) ? Wq : (z == 1) ? Wk : Wv;
    uint16_t* WT = (z == 0) ? WqT : (z == 1) ? WkT : WvT;
    const int col = bx * 256 + t;
    for (int kc = 0; kc < 16; ++kc) {
      u32x4 wv;
      #pragma unroll
      for (int p = 0; p < 4; ++p) {
        float f0 = W[(size_t)(kc * 8 + 2 * p) * DH + col];
        float f1 = W[(size_t)(kc * 8 + 2 * p + 1) * DH + col];
        wv[p] = cvt_pk_bf16(f0, f1);
      }
      *(u32x4*)(WT + (size_t)col * 128 + kc * 8) = wv;
    }
  } else {
    const int col = t & 127, ksub = t >> 7;
    const int kbase = bx * 256 + ksub * 128;
    for (int kc = 0; kc < 16; ++kc) {
      const int k0 = kbase + kc * 8;
      u32x4 wv;
      #pragma unroll
      for (int p = 0; p < 4; ++p) {
        float f0 = Wo[(size_t)(k0 + 2 * p) * DDIM + col];
        float f1 = Wo[(size_t)(k0 + 2 * p + 1) * DDIM + col];
        wv[p] = cvt_pk_bf16(f0, f1);
      }
      *(u32x4*)(WoT + (size_t)col * DH + k0) = wv;
    }
  }
}

// ---------------- Kernel 1: Q/K/V projections ----------------
// C = A[8192x128] @ W[128x2048] + b, stored bf16 in attention layouts.
// q3/k3: u16 idx = n*2048 + ((f>>3)&1)*1024 + (f>>4)*8 + (f&7)   (f = i*16+h)
// v3   : u16 idx = n*2048 + (f&15)*128 + (f>>4)                  ([h][j])
//
// Store path: stage the 32x512 panel in LDS in destination layout, then
// coalesced dwordx4 bursts (q3/k3: 2x512B per token; v3: 16x64B per token).
__global__ __launch_bounds__(256) void proj_kernel(
    const float* __restrict__ q, const float* __restrict__ kin,
    const float* __restrict__ v,
    const uint16_t* __restrict__ WqT, const uint16_t* __restrict__ WkT,
    const uint16_t* __restrict__ WvT,
    const float* __restrict__ bq, const float* __restrict__ bk,
    const float* __restrict__ bv,
    uint16_t* __restrict__ q3, uint16_t* __restrict__ k3,
    uint16_t* __restrict__ v3) {
  __shared__ uint16_t tile[32 * 512];   // 32 KB, destination-layout staging
  const int z = blockIdx.z;
  const float* A = (z == 0) ? q : (z == 1) ? kin : v;
  const uint16_t* WT = (z == 0) ? WqT : (z == 1) ? WkT : WvT;
  const float* bias = (z == 0) ? bq : (z == 1) ? bk : bv;
  uint16_t* dst = (z == 0) ? q3 : (z == 1) ? k3 : v3;

  const int w = threadIdx.x >> 6;
  const int l = threadIdx.x & 63;
  const int il = l & 31, hi = l >> 5;
  const int rowbase = blockIdx.x * 32;
  const int by = blockIdx.y;
  const int colbase = by * 512 + w * 128;

  f32x16 acc0 = {}, acc1 = {}, acc2 = {}, acc3 = {};
  #pragma unroll
  for (int ks = 0; ks < 8; ++ks) {
    const int kk = ks * 16 + hi * 8;
    const float* ap = A + (size_t)(rowbase + il) * DDIM + kk;
    float4 a0 = *(const float4*)ap;
    float4 a1 = *(const float4*)(ap + 4);
    u32x4 av = { cvt_pk_bf16(a0.x, a0.y), cvt_pk_bf16(a0.z, a0.w),
                 cvt_pk_bf16(a1.x, a1.y), cvt_pk_bf16(a1.z, a1.w) };
    bf16x8 af = __builtin_bit_cast(bf16x8, av);
    bf16x8 b0 = *(const bf16x8*)(WT + (size_t)(colbase + 0 * 32 + il) * 128 + kk);
    bf16x8 b1 = *(const bf16x8*)(WT + (size_t)(colbase + 1 * 32 + il) * 128 + kk);
    bf16x8 b2 = *(const bf16x8*)(WT + (size_t)(colbase + 2 * 32 + il) * 128 + kk);
    bf16x8 b3 = *(const bf16x8*)(WT + (size_t)(colbase + 3 * 32 + il) * 128 + kk);
    acc0 = __builtin_amdgcn_mfma_f32_32x32x16_bf16(af, b0, acc0, 0, 0, 0);
    acc1 = __builtin_amdgcn_mfma_f32_32x32x16_bf16(af, b1, acc1, 0, 0, 0);
    acc2 = __builtin_amdgcn_mfma_f32_32x32x16_bf16(af, b2, acc2, 0, 0, 0);
    acc3 = __builtin_amdgcn_mfma_f32_32x32x16_bf16(af, b3, acc3, 0, 0, 0);
  }
  const bool vlayout = (z == 2);
  // Stage into LDS in destination layout (local col lc = col - by*512):
  //   q3/k3: lds[rr*512 + ((lc>>3)&1)*256 + (lc>>4)*8 + (lc&7)]
  //   v3   : lds[rr*512 + (lc&15)*32 + (lc>>4)]
  #pragma unroll
  for (int nt = 0; nt < 4; ++nt) {
    const f32x16 acc = (nt == 0) ? acc0 : (nt == 1) ? acc1 : (nt == 2) ? acc2 : acc3;
    const int lc = w * 128 + nt * 32 + il;
    const float bval = bias[by * 512 + lc];
    int cm;
    if (!vlayout) cm = ((lc >> 3) & 1) * 256 + (lc >> 4) * 8 + (lc & 7);
    else          cm = (lc & 15) * 32 + (lc >> 4);
    #pragma unroll
    for (int r = 0; r < 16; ++r) {
      const int rr = crow4(r, hi);
      tile[rr * 512 + cm] = bf16bits(acc[r] + bval);
    }
  }
  __syncthreads();
  // Coalesced store: 2048 16B-units, 8 per thread; wave t>>6 streams full rows.
  const int t = threadIdx.x;
  #pragma unroll
  for (int kk2 = 0; kk2 < 8; ++kk2) {
    const int u = t + kk2 * 256;
    const int rr = u >> 6, qq = u & 63;
    u32x4 val = *(const u32x4*)(tile + rr * 512 + qq * 8);
    const size_t n = rowbase + rr;
    size_t gaddr;
    if (!vlayout) gaddr = n * 2048 + (size_t)(qq >> 5) * 1024 + (size_t)by * 256 + (qq & 31) * 8;
    else          gaddr = n * 2048 + (size_t)(qq >> 2) * 128  + (size_t)by * 32  + (qq & 3) * 8;
    *(u32x4*)(dst + gaddr) = val;
  }
}

// ---------------- Kernel 2: per-token attention ----------------
// One WG (4 waves) per token. S^T = k3 · q3^T (so softmax over i is a
// wave-local row reduction), fold 1/denom into P, P->bf16 via cvt_pk +
// permlane32_swap, PV with per-wave j-slab + LDS 4-way reduce.
// out3 (bf16 [n][f], f=i*16+h) overwrites the q3 region.
__global__ __launch_bounds__(256) void attn_kernel(
    const uint16_t* q3, const uint16_t* __restrict__ k3,
    const uint16_t* __restrict__ v3, uint16_t* out3) {
  __shared__ float part[4][128][16];
  const int n = blockIdx.x;
  const int w = threadIdx.x >> 6;
  const int l = threadIdx.x & 63;
  const int il = l & 31, hi = l >> 5;
  const uint16_t* qb = q3 + (size_t)n * 2048;
  const uint16_t* kb = k3 + (size_t)n * 2048;
  const uint16_t* vb = v3 + (size_t)n * 2048;

  // A-frag: k3 rows j = 32w+il, k = h = hi*8..+7
  bf16x8 af = *(const bf16x8*)(kb + hi * 1024 + (size_t)(w * 32 + il) * 8);
  f32x16 d0 = {}, d1 = {}, d2 = {}, d3 = {};
  {
    bf16x8 bq0 = *(const bf16x8*)(qb + hi * 1024 + (size_t)(0 * 32 + il) * 8);
    bf16x8 bq1 = *(const bf16x8*)(qb + hi * 1024 + (size_t)(1 * 32 + il) * 8);
    bf16x8 bq2 = *(const bf16x8*)(qb + hi * 1024 + (size_t)(2 * 32 + il) * 8);
    bf16x8 bq3 = *(const bf16x8*)(qb + hi * 1024 + (size_t)(3 * 32 + il) * 8);
    d0 = __builtin_amdgcn_mfma_f32_32x32x16_bf16(af, bq0, d0, 0, 0, 0);
    d1 = __builtin_amdgcn_mfma_f32_32x32x16_bf16(af, bq1, d1, 0, 0, 0);
    d2 = __builtin_amdgcn_mfma_f32_32x32x16_bf16(af, bq2, d2, 0, 0, 0);
    d3 = __builtin_amdgcn_mfma_f32_32x32x16_bf16(af, bq3, d3, 0, 0, 0);
  }
  // softmax over i (cols): per row (reg,hi): sum over 4 tiles + 32-lane butterfly
  const float CEXP = 1.4426950408889634f * 0.08838834764831845f; // log2(e)/sqrt(128)
  #pragma unroll
  for (int r = 0; r < 16; ++r) {
    float e0 = exp2f(d0[r] * CEXP), e1 = exp2f(d1[r] * CEXP);
    float e2 = exp2f(d2[r] * CEXP), e3 = exp2f(d3[r] * CEXP);
    float s = (e0 + e1) + (e2 + e3);
    s += __shfl_xor(s, 1);  s += __shfl_xor(s, 2);  s += __shfl_xor(s, 4);
    s += __shfl_xor(s, 8);  s += __shfl_xor(s, 16);
    const float rs = __builtin_amdgcn_rcpf(s);
    d0[r] = e0 * rs; d1[r] = e1 * rs; d2[r] = e2 * rs; d3[r] = e3 * rs;
  }
  // V B-frags: col h = il (h<16 valid), k j = 32w + 16ks + 8hi + c
  bf16x8 vf0 = *(const bf16x8*)(vb + (size_t)(il & 15) * 128 + (w * 32 + hi * 8));
  bf16x8 vf1 = *(const bf16x8*)(vb + (size_t)(il & 15) * 128 + (w * 32 + 16 + hi * 8));

  f32x16 o[4];
  #pragma unroll
  for (int mi = 0; mi < 4; ++mi) {
    const f32x16 p = (mi == 0) ? d0 : (mi == 1) ? d1 : (mi == 2) ? d2 : d3;
    uint32_t pk0 = cvt_pk_bf16(p[0],  p[1]),  pk1 = cvt_pk_bf16(p[2],  p[3]);
    uint32_t pk2 = cvt_pk_bf16(p[4],  p[5]),  pk3 = cvt_pk_bf16(p[6],  p[7]);
    uint32_t pk4 = cvt_pk_bf16(p[8],  p[9]),  pk5 = cvt_pk_bf16(p[10], p[11]);
    uint32_t pk6 = cvt_pk_bf16(p[12], p[13]), pk7 = cvt_pk_bf16(p[14], p[15]);
    // swap(x,y): r[0] = [x_lo | y_lo], r[1] = [x_hi | y_hi]
    auto sA = __builtin_amdgcn_permlane32_swap(pk0, pk2, false, false); // W0, W2
    auto sB = __builtin_amdgcn_permlane32_swap(pk1, pk3, false, false); // W1, W3
    auto sC = __builtin_amdgcn_permlane32_swap(pk4, pk6, false, false); // W0',W2'
    auto sD = __builtin_amdgcn_permlane32_swap(pk5, pk7, false, false); // W1',W3'
    u32x4 fw0 = { sA[0], sB[0], sA[1], sB[1] };
    u32x4 fw1 = { sC[0], sD[0], sC[1], sD[1] };
    f32x16 oz = {};
    oz    = __builtin_amdgcn_mfma_f32_32x32x16_bf16(__builtin_bit_cast(bf16x8, fw0), vf0, oz, 0, 0, 0);
    o[mi] = __builtin_amdgcn_mfma_f32_32x32x16_bf16(__builtin_bit_cast(bf16x8, fw1), vf1, oz, 0, 0, 0);
  }
  if (il < 16) {
    #pragma unroll
    for (int mi = 0; mi < 4; ++mi) {
      #pragma unroll
      for (int r = 0; r < 16; ++r)
        part[w][mi * 32 + crow4(r, hi)][il] = o[mi][r];
    }
  }
  __syncthreads();
  const int t = threadIdx.x;
  const int i0 = t >> 1, h0 = (t & 1) * 8;
  float sv[8];
  #pragma unroll
  for (int e = 0; e < 8; ++e)
    sv[e] = part[0][i0][h0 + e] + part[1][i0][h0 + e] +
            part[2][i0][h0 + e] + part[3][i0][h0 + e];
  u32x4 ov = { cvt_pk_bf16(sv[0], sv[1]), cvt_pk_bf16(sv[2], sv[3]),
               cvt_pk_bf16(sv[4], sv[5]), cvt_pk_bf16(sv[6], sv[7]) };
  *(u32x4*)(out3 + (size_t)n * 2048 + t * 8) = ov;
}

// ---------------- Kernel 3: output projection ----------------
// out = out3[8192x2048](bf16) @ Wo + bo, f32 out. K-split 2 per block.
__global__ __launch_bounds__(512) void outproj_kernel(
    const uint16_t* __restrict__ out3, const uint16_t* __restrict__ WoT,
    const float* __restrict__ bo, float* __restrict__ out) {
  __shared__ float part[4][32][32];
  const int w = threadIdx.x >> 6;
  const int l = threadIdx.x & 63;
  const int il = l & 31, hi = l >> 5;
  const int nt = w >> 1, ksv = w & 1;
  const int rowbase = blockIdx.x * 32;
  f32x16 acc = {};
  #pragma unroll 4
  for (int kb = 0; kb < 64; ++kb) {
    const int kk = ksv * 1024 + kb * 16 + hi * 8;
    bf16x8 afr = *(const bf16x8*)(out3 + (size_t)(rowbase + il) * DH + kk);
    bf16x8 bfr = *(const bf16x8*)(WoT + (size_t)(nt * 32 + il) * DH + kk);
    acc = __builtin_amdgcn_mfma_f32_32x32x16_bf16(afr, bfr, acc, 0, 0, 0);
  }
  if (ksv == 1) {
    #pragma unroll
    for (int r = 0; r < 16; ++r) part[nt][crow4(r, hi)][il] = acc[r];
  }
  __syncthreads();
  if (ksv == 0) {
    const int col = nt * 32 + il;
    const float bval = bo[col];
    #pragma unroll
    for (int r = 0; r < 16; ++r) {
      const int rr = crow4(r, hi);
      out[(size_t)(rowbase + rr) * DDIM + col] = acc[r] + part[nt][rr][il] + bval;
    }
  }
}

extern "C" void kernel_launch(void* const* d_in, const int* in_sizes, int n_in,
                              void* d_out, int out_size, void* d_ws, size_t ws_size,
                              hipStream_t stream) {
  (void)in_sizes; (void)n_in; (void)out_size; (void)ws_size;
  const float* q  = (const float*)d_in[0];
  const float* k  = (const float*)d_in[1];
  const float* v  = (const float*)d_in[2];
  const float* Wq = (const float*)d_in[3];
  const float* bq = (const float*)d_in[4];
  const float* Wk = (const float*)d_in[5];
  const float* bk = (const float*)d_in[6];
  const float* Wv = (const float*)d_in[7];
  const float* bv = (const float*)d_in[8];
  const float* Wo = (const float*)d_in[9];
  const float* bo = (const float*)d_in[10];
  float* out = (float*)d_out;

  char* ws = (char*)d_ws;
  const size_t MB = 1024ull * 1024ull;
  uint16_t* q3  = (uint16_t*)(ws);             // 32MB; becomes out3
  uint16_t* k3  = (uint16_t*)(ws + 32 * MB);
  uint16_t* v3  = (uint16_t*)(ws + 64 * MB);
  uint16_t* WqT = (uint16_t*)(ws + 96 * MB);   // 512KB each
  uint16_t* WkT = WqT + (size_t)DH * 128;
  uint16_t* WvT = WkT + (size_t)DH * 128;
  uint16_t* WoT = WvT + (size_t)DH * 128;

  prep_weights<<<dim3(8, 4), 256, 0, stream>>>(Wq, Wk, Wv, Wo, WqT, WkT, WvT, WoT);
  proj_kernel<<<dim3(256, 4, 3), 256, 0, stream>>>(q, k, v, WqT, WkT, WvT,
                                                   bq, bk, bv, q3, k3, v3);
  attn_kernel<<<dim3(NTOK), 256, 0, stream>>>(q3, k3, v3, q3);
  outproj_kernel<<<dim3(256), 512, 0, stream>>>(q3, WoT, bo, out);
}

// Round 3
// 142.773 us; speedup vs baseline: 1.9669x; 1.2966x over previous
//
#include <hip/hip_runtime.h>
#include <hip/hip_bf16.h>
#include <stdint.h>

// Problem: N=8192 tokens, D=128, HEADS=16, dh=2048.
// Pipeline: prep weights (fragment-major WT) -> q3/k3/v3 projections
//           (A staged in LDS, coalesced B-frag loads, dest-layout LDS epilogue)
//           -> per-token attention -> output projection.
//
// ws layout (~98 MB):
//   [0,32M)   q3  bf16 [n]{(h>>3)*1024 + i*8 + (h&7)}  -- later out3 [n][f]
//   [32,64M)  k3  bf16 same layout
//   [64,96M)  v3  bf16 [n]{(j>>3)*128 + h*8 + (j&7)}   (fragment units for PV)
//   [96M..)   WTq/WTk/WTv bf16 frag-major [g(64)][ks(8)][hi(2)][il(32)][8],
//             WoT bf16 [128 col][2048 k]

#define NTOK 8192
#define DDIM 128
#define DH   2048

typedef float   f32x16 __attribute__((ext_vector_type(16)));
typedef __bf16  bf16x8 __attribute__((ext_vector_type(8)));
typedef uint32_t u32x4 __attribute__((ext_vector_type(4)));

static __device__ __forceinline__ uint32_t cvt_pk_bf16(float lo, float hi) {
  uint32_t r;
  asm("v_cvt_pk_bf16_f32 %0, %1, %2" : "=v"(r) : "v"(lo), "v"(hi));
  return r;
}
// C/D row mapping for mfma_f32_32x32x16: row = (r&3) + 8*(r>>2) + 4*hi, col = lane&31
static __device__ __forceinline__ int crow4(int r, int hi) {
  return (r & 3) + 8 * (r >> 2) + 4 * hi;
}

// ---------------- Kernel 0: weight prep ----------------
// Wq/Wk/Wv f32 [128][2048] -> WT bf16 frag-major: [g=col>>5][ks][hi][il=col&31][8]
// Wo f32 [2048][128] -> WoT bf16 [128 col][2048 k]
__global__ __launch_bounds__(256) void prep_weights(
    const float* __restrict__ Wq, const float* __restrict__ Wk,
    const float* __restrict__ Wv, const float* __restrict__ Wo,
    uint16_t* __restrict__ WqT, uint16_t* __restrict__ WkT,
    uint16_t* __restrict__ WvT, uint16_t* __restrict__ WoT) {
  const int t = threadIdx.x, bx = blockIdx.x, z = blockIdx.y;
  if (z < 3) {
    const float* W = (z == 0) ? Wq : (z == 1) ? Wk : Wv;
    uint16_t* WT = (z == 0) ? WqT : (z == 1) ? WkT : WvT;
    const int col = bx * 256 + t;
    const int g = col >> 5, il = col & 31;
    for (int kc = 0; kc < 16; ++kc) {   // kc = k>>3 : ks = kc>>1, hi = kc&1
      u32x4 wv;
      #pragma unroll
      for (int p = 0; p < 4; ++p) {
        float f0 = W[(size_t)(kc * 8 + 2 * p) * DH + col];
        float f1 = W[(size_t)(kc * 8 + 2 * p + 1) * DH + col];
        wv[p] = cvt_pk_bf16(f0, f1);
      }
      *(u32x4*)(WT + (size_t)g * 4096 + (kc >> 1) * 512 + (kc & 1) * 256 + il * 8) = wv;
    }
  } else {
    const int col = t & 127, ksub = t >> 7;
    const int kbase = bx * 256 + ksub * 128;
    for (int kc = 0; kc < 16; ++kc) {
      const int k0 = kbase + kc * 8;
      u32x4 wv;
      #pragma unroll
      for (int p = 0; p < 4; ++p) {
        float f0 = Wo[(size_t)(k0 + 2 * p) * DDIM + col];
        float f1 = Wo[(size_t)(k0 + 2 * p + 1) * DDIM + col];
        wv[p] = cvt_pk_bf16(f0, f1);
      }
      *(u32x4*)(WoT + (size_t)col * DH + k0) = wv;
    }
  }
}

// ---------------- Kernel 1: Q/K/V projections ----------------
// C = A[8192x128] @ W[128x2048] + b, bf16 out in attention layouts.
// q3/k3 unit: idx = n*2048 + (h>>3)*1024 + i*8 + (h&7)        (f = i*16+h)
// v3   unit: idx = n*2048 + (j>>3)*128 + h*8 + (j&7)          (f = j*16+h)
__global__ __launch_bounds__(256, 3) void proj_kernel(
    const float* __restrict__ q, const float* __restrict__ kin,
    const float* __restrict__ v,
    const uint16_t* __restrict__ WqT, const uint16_t* __restrict__ WkT,
    const uint16_t* __restrict__ WvT,
    const float* __restrict__ bq, const float* __restrict__ bk,
    const float* __restrict__ bv,
    uint16_t* __restrict__ q3, uint16_t* __restrict__ k3,
    uint16_t* __restrict__ v3) {
  __shared__ uint16_t astage[4096];    // A tile, frag layout [ks][hi][il][8]
  __shared__ uint16_t tile[32 * 512];  // 32 KB destination-layout staging
  const int z = blockIdx.z;
  const float* A = (z == 0) ? q : (z == 1) ? kin : v;
  const uint16_t* WTf = (z == 0) ? WqT : (z == 1) ? WkT : WvT;
  const float* bias = (z == 0) ? bq : (z == 1) ? bk : bv;
  uint16_t* dst = (z == 0) ? q3 : (z == 1) ? k3 : v3;
  const bool vlayout = (z == 2);

  const int t = threadIdx.x;
  const int w = t >> 6, l = t & 63;
  const int il = l & 31, hi = l >> 5;
  const int T = blockIdx.x, by = blockIdx.y;
  const int rowbase = T * 32;

  // ---- stage A tile (32x128 f32 -> bf16 frag layout), coalesced ----
  {
    const int rp = t >> 3, kc = t & 7;
    const float* ap = A + ((size_t)rowbase + rp) * DDIM + kc * 16;
    float4 f0 = *(const float4*)(ap + 0);
    float4 f1 = *(const float4*)(ap + 4);
    float4 f2 = *(const float4*)(ap + 8);
    float4 f3 = *(const float4*)(ap + 12);
    u32x4 u0 = { cvt_pk_bf16(f0.x, f0.y), cvt_pk_bf16(f0.z, f0.w),
                 cvt_pk_bf16(f1.x, f1.y), cvt_pk_bf16(f1.z, f1.w) };
    u32x4 u1 = { cvt_pk_bf16(f2.x, f2.y), cvt_pk_bf16(f2.z, f2.w),
                 cvt_pk_bf16(f3.x, f3.y), cvt_pk_bf16(f3.z, f3.w) };
    *(u32x4*)(astage + kc * 512 + rp * 8) = u0;        // hi=0 half
    *(u32x4*)(astage + kc * 512 + 256 + rp * 8) = u1;  // hi=1 half
  }
  __syncthreads();

  const int lo = hi * 256 + il * 8;
  bf16x8 af[8];
  #pragma unroll
  for (int ks = 0; ks < 8; ++ks)
    af[ks] = *(const bf16x8*)(astage + ks * 512 + lo);

  const uint16_t* WB = WTf + (size_t)(by * 16 + w * 4) * 4096;
  f32x16 acc0 = {}, acc1 = {}, acc2 = {}, acc3 = {};
  #pragma unroll
  for (int ks = 0; ks < 8; ++ks) {
    bf16x8 b0 = *(const bf16x8*)(WB + 0 * 4096 + ks * 512 + lo);
    bf16x8 b1 = *(const bf16x8*)(WB + 1 * 4096 + ks * 512 + lo);
    bf16x8 b2 = *(const bf16x8*)(WB + 2 * 4096 + ks * 512 + lo);
    bf16x8 b3 = *(const bf16x8*)(WB + 3 * 4096 + ks * 512 + lo);
    acc0 = __builtin_amdgcn_mfma_f32_32x32x16_bf16(af[ks], b0, acc0, 0, 0, 0);
    acc1 = __builtin_amdgcn_mfma_f32_32x32x16_bf16(af[ks], b1, acc1, 0, 0, 0);
    acc2 = __builtin_amdgcn_mfma_f32_32x32x16_bf16(af[ks], b2, acc2, 0, 0, 0);
    acc3 = __builtin_amdgcn_mfma_f32_32x32x16_bf16(af[ks], b3, acc3, 0, 0, 0);
  }

  // ---- stage into LDS in destination layout (local col lc) ----
  //   q3/k3: cm = ((lc>>3)&1)*256 + (lc>>4)*8 + (lc&7), XOR-swz bit8->bit4
  //   v3   : cm = ((lc>>7)&3)*128 + (lc&15)*8 + ((lc>>4)&7)   (bank-spread)
  #pragma unroll
  for (int nt = 0; nt < 4; ++nt) {
    const f32x16 acc = (nt == 0) ? acc0 : (nt == 1) ? acc1 : (nt == 2) ? acc2 : acc3;
    const int lc = w * 128 + nt * 32 + il;
    const float bval = bias[by * 512 + lc];
    int cm;
    if (!vlayout) {
      const int c = (lc >> 3) & 1;
      cm = (c * 256 + (lc >> 4) * 8 + (lc & 7)) ^ (c << 4);
    } else {
      cm = ((lc >> 7) & 3) * 128 + (lc & 15) * 8 + ((lc >> 4) & 7);
    }
    #pragma unroll
    for (int r = 0; r < 16; r += 2) {
      const int rr0 = crow4(r, hi);              // r even: rr1 = rr0+1
      const uint32_t pk = cvt_pk_bf16(acc[r] + bval, acc[r + 1] + bval);
      tile[rr0 * 512 + cm] = (uint16_t)pk;
      tile[(rr0 + 1) * 512 + cm] = (uint16_t)(pk >> 16);
    }
  }
  __syncthreads();

  // ---- coalesced store: 2048 16B-units, 8 per thread ----
  #pragma unroll
  for (int kk2 = 0; kk2 < 8; ++kk2) {
    const int u = t + kk2 * 256;
    const int rr = u >> 6, qq = u & 63;
    int toff;
    size_t gaddr;
    const size_t n = rowbase + rr;
    if (!vlayout) {
      toff = (qq * 8) ^ ((qq >> 5) << 4);   // undo stage swizzle
      gaddr = n * 2048 + (size_t)(qq >> 5) * 1024 + (size_t)by * 256 + (qq & 31) * 8;
    } else {
      toff = qq * 8;
      gaddr = n * 2048 + (size_t)by * 512 + (size_t)(qq >> 4) * 128 + (qq & 15) * 8;
    }
    u32x4 val = *(const u32x4*)(tile + rr * 512 + toff);
    *(u32x4*)(dst + gaddr) = val;
  }
}

// ---------------- Kernel 2: per-token attention ----------------
// One WG (4 waves) per token. S^T = k3 · q3^T (softmax over i is a wave-local
// row reduction), fold 1/denom into P, P->bf16 via cvt_pk + permlane32_swap,
// PV with per-wave j-slab + LDS 4-way reduce. out3 overwrites q3 region.
__global__ __launch_bounds__(256) void attn_kernel(
    const uint16_t* q3, const uint16_t* __restrict__ k3,
    const uint16_t* __restrict__ v3, uint16_t* out3) {
  __shared__ float part[4][128][16];
  const int n = blockIdx.x;
  const int w = threadIdx.x >> 6;
  const int l = threadIdx.x & 63;
  const int il = l & 31, hi = l >> 5;
  const uint16_t* qb = q3 + (size_t)n * 2048;
  const uint16_t* kb = k3 + (size_t)n * 2048;
  const uint16_t* vb = v3 + (size_t)n * 2048;

  // A-frag: k3 rows j = 32w+il, k = h = hi*8..+7
  bf16x8 af = *(const bf16x8*)(kb + hi * 1024 + (size_t)(w * 32 + il) * 8);
  f32x16 d0 = {}, d1 = {}, d2 = {}, d3 = {};
  {
    bf16x8 bq0 = *(const bf16x8*)(qb + hi * 1024 + (size_t)(0 * 32 + il) * 8);
    bf16x8 bq1 = *(const bf16x8*)(qb + hi * 1024 + (size_t)(1 * 32 + il) * 8);
    bf16x8 bq2 = *(const bf16x8*)(qb + hi * 1024 + (size_t)(2 * 32 + il) * 8);
    bf16x8 bq3 = *(const bf16x8*)(qb + hi * 1024 + (size_t)(3 * 32 + il) * 8);
    d0 = __builtin_amdgcn_mfma_f32_32x32x16_bf16(af, bq0, d0, 0, 0, 0);
    d1 = __builtin_amdgcn_mfma_f32_32x32x16_bf16(af, bq1, d1, 0, 0, 0);
    d2 = __builtin_amdgcn_mfma_f32_32x32x16_bf16(af, bq2, d2, 0, 0, 0);
    d3 = __builtin_amdgcn_mfma_f32_32x32x16_bf16(af, bq3, d3, 0, 0, 0);
  }
  // softmax over i (cols): per row (reg,hi): sum over 4 tiles + 32-lane butterfly
  const float CEXP = 1.4426950408889634f * 0.08838834764831845f; // log2(e)/sqrt(128)
  #pragma unroll
  for (int r = 0; r < 16; ++r) {
    float e0 = exp2f(d0[r] * CEXP), e1 = exp2f(d1[r] * CEXP);
    float e2 = exp2f(d2[r] * CEXP), e3 = exp2f(d3[r] * CEXP);
    float s = (e0 + e1) + (e2 + e3);
    s += __shfl_xor(s, 1);  s += __shfl_xor(s, 2);  s += __shfl_xor(s, 4);
    s += __shfl_xor(s, 8);  s += __shfl_xor(s, 16);
    const float rs = __builtin_amdgcn_rcpf(s);
    d0[r] = e0 * rs; d1[r] = e1 * rs; d2[r] = e2 * rs; d3[r] = e3 * rs;
  }
  // V B-frags from v3 frag layout [j>>3][h][8]: unit (jg = w*4+hi (+2), h = il&15)
  bf16x8 vf0 = *(const bf16x8*)(vb + (size_t)(w * 4 + hi) * 128 + (il & 15) * 8);
  bf16x8 vf1 = *(const bf16x8*)(vb + (size_t)(w * 4 + hi + 2) * 128 + (il & 15) * 8);

  f32x16 o[4];
  #pragma unroll
  for (int mi = 0; mi < 4; ++mi) {
    const f32x16 p = (mi == 0) ? d0 : (mi == 1) ? d1 : (mi == 2) ? d2 : d3;
    uint32_t pk0 = cvt_pk_bf16(p[0],  p[1]),  pk1 = cvt_pk_bf16(p[2],  p[3]);
    uint32_t pk2 = cvt_pk_bf16(p[4],  p[5]),  pk3 = cvt_pk_bf16(p[6],  p[7]);
    uint32_t pk4 = cvt_pk_bf16(p[8],  p[9]),  pk5 = cvt_pk_bf16(p[10], p[11]);
    uint32_t pk6 = cvt_pk_bf16(p[12], p[13]), pk7 = cvt_pk_bf16(p[14], p[15]);
    // swap(x,y): r[0] = [x_lo | y_lo], r[1] = [x_hi | y_hi]
    auto sA = __builtin_amdgcn_permlane32_swap(pk0, pk2, false, false); // W0, W2
    auto sB = __builtin_amdgcn_permlane32_swap(pk1, pk3, false, false); // W1, W3
    auto sC = __builtin_amdgcn_permlane32_swap(pk4, pk6, false, false); // W0',W2'
    auto sD = __builtin_amdgcn_permlane32_swap(pk5, pk7, false, false); // W1',W3'
    u32x4 fw0 = { sA[0], sB[0], sA[1], sB[1] };
    u32x4 fw1 = { sC[0], sD[0], sC[1], sD[1] };
    f32x16 oz = {};
    oz    = __builtin_amdgcn_mfma_f32_32x32x16_bf16(__builtin_bit_cast(bf16x8, fw0), vf0, oz, 0, 0, 0);
    o[mi] = __builtin_amdgcn_mfma_f32_32x32x16_bf16(__builtin_bit_cast(bf16x8, fw1), vf1, oz, 0, 0, 0);
  }
  if (il < 16) {
    #pragma unroll
    for (int mi = 0; mi < 4; ++mi) {
      #pragma unroll
      for (int r = 0; r < 16; ++r)
        part[w][mi * 32 + crow4(r, hi)][il] = o[mi][r];
    }
  }
  __syncthreads();
  const int t = threadIdx.x;
  const int i0 = t >> 1, h0 = (t & 1) * 8;
  float sv[8];
  #pragma unroll
  for (int e = 0; e < 8; ++e)
    sv[e] = part[0][i0][h0 + e] + part[1][i0][h0 + e] +
            part[2][i0][h0 + e] + part[3][i0][h0 + e];
  u32x4 ov = { cvt_pk_bf16(sv[0], sv[1]), cvt_pk_bf16(sv[2], sv[3]),
               cvt_pk_bf16(sv[4], sv[5]), cvt_pk_bf16(sv[6], sv[7]) };
  *(u32x4*)(out3 + (size_t)n * 2048 + t * 8) = ov;
}

// ---------------- Kernel 3: output projection ----------------
// out = out3[8192x2048](bf16) @ Wo + bo, f32 out. K-split 2 per block.
__global__ __launch_bounds__(512) void outproj_kernel(
    const uint16_t* __restrict__ out3, const uint16_t* __restrict__ WoT,
    const float* __restrict__ bo, float* __restrict__ out) {
  __shared__ float part[4][32][32];
  const int w = threadIdx.x >> 6;
  const int l = threadIdx.x & 63;
  const int il = l & 31, hi = l >> 5;
  const int nt = w >> 1, ksv = w & 1;
  const int rowbase = blockIdx.x * 32;
  f32x16 acc = {};
  #pragma unroll 4
  for (int kb = 0; kb < 64; ++kb) {
    const int kk = ksv * 1024 + kb * 16 + hi * 8;
    bf16x8 afr = *(const bf16x8*)(out3 + (size_t)(rowbase + il) * DH + kk);
    bf16x8 bfr = *(const bf16x8*)(WoT + (size_t)(nt * 32 + il) * DH + kk);
    acc = __builtin_amdgcn_mfma_f32_32x32x16_bf16(afr, bfr, acc, 0, 0, 0);
  }
  if (ksv == 1) {
    #pragma unroll
    for (int r = 0; r < 16; ++r) part[nt][crow4(r, hi)][il] = acc[r];
  }
  __syncthreads();
  if (ksv == 0) {
    const int col = nt * 32 + il;
    const float bval = bo[col];
    #pragma unroll
    for (int r = 0; r < 16; ++r) {
      const int rr = crow4(r, hi);
      out[(size_t)(rowbase + rr) * DDIM + col] = acc[r] + part[nt][rr][il] + bval;
    }
  }
}

extern "C" void kernel_launch(void* const* d_in, const int* in_sizes, int n_in,
                              void* d_out, int out_size, void* d_ws, size_t ws_size,
                              hipStream_t stream) {
  (void)in_sizes; (void)n_in; (void)out_size; (void)ws_size;
  const float* q  = (const float*)d_in[0];
  const float* k  = (const float*)d_in[1];
  const float* v  = (const float*)d_in[2];
  const float* Wq = (const float*)d_in[3];
  const float* bq = (const float*)d_in[4];
  const float* Wk = (const float*)d_in[5];
  const float* bk = (const float*)d_in[6];
  const float* Wv = (const float*)d_in[7];
  const float* bv = (const float*)d_in[8];
  const float* Wo = (const float*)d_in[9];
  const float* bo = (const float*)d_in[10];
  float* out = (float*)d_out;

  char* ws = (char*)d_ws;
  const size_t MB = 1024ull * 1024ull;
  uint16_t* q3  = (uint16_t*)(ws);             // 32MB; becomes out3
  uint16_t* k3  = (uint16_t*)(ws + 32 * MB);
  uint16_t* v3  = (uint16_t*)(ws + 64 * MB);
  uint16_t* WqT = (uint16_t*)(ws + 96 * MB);   // 512KB each
  uint16_t* WkT = WqT + (size_t)DH * 128;
  uint16_t* WvT = WkT + (size_t)DH * 128;
  uint16_t* WoT = WvT + (size_t)DH * 128;

  prep_weights<<<dim3(8, 4), 256, 0, stream>>>(Wq, Wk, Wv, Wo, WqT, WkT, WvT, WoT);
  proj_kernel<<<dim3(256, 4, 3), 256, 0, stream>>>(q, k, v, WqT, WkT, WvT,
                                                   bq, bk, bv, q3, k3, v3);
  attn_kernel<<<dim3(NTOK), 256, 0, stream>>>(q3, k3, v3, q3);
  outproj_kernel<<<dim3(256), 512, 0, stream>>>(q3, WoT, bo, out);
}

// Round 4
// 136.305 us; speedup vs baseline: 2.0603x; 1.0475x over previous
//
#include <hip/hip_runtime.h>
#include <hip/hip_bf16.h>
#include <stdint.h>

// Problem: N=8192 tokens, D=128, HEADS=16, dh=2048.
// Pipeline: prep weights (fragment-major WT) -> q3/k3/v3 projections
//           (q3 pre-scaled by log2(e)/sqrt(D); A staged in LDS; coalesced
//           B-frag loads; dest-layout LDS epilogue)
//           -> per-token attention (DPP-reduce softmax, swizzled partials)
//           -> output projection.
//
// ws layout (~98 MB):
//   [0,32M)   q3  bf16 [n]{(h>>3)*1024 + i*8 + (h&7)}  (scaled by CEXP)
//             -- later overwritten by out3 [n][f]
//   [32,64M)  k3  bf16 same layout (unscaled)
//   [64,96M)  v3  bf16 [n]{(j>>3)*128 + h*8 + (j&7)}   (fragment units for PV)
//   [96M..)   WTq/WTk/WTv bf16 frag-major [g(64)][ks(8)][hi(2)][il(32)][8],
//             WoT bf16 [128 col][2048 k]

#define NTOK 8192
#define DDIM 128
#define DH   2048

typedef float   f32x16 __attribute__((ext_vector_type(16)));
typedef __bf16  bf16x8 __attribute__((ext_vector_type(8)));
typedef uint32_t u32x4 __attribute__((ext_vector_type(4)));

static __device__ __forceinline__ uint32_t cvt_pk_bf16(float lo, float hi) {
  uint32_t r;
  asm("v_cvt_pk_bf16_f32 %0, %1, %2" : "=v"(r) : "v"(lo), "v"(hi));
  return r;
}
// C/D row mapping for mfma_f32_32x32x16: row = (r&3) + 8*(r>>2) + 4*hi, col = lane&31
static __device__ __forceinline__ int crow4(int r, int hi) {
  return (r & 3) + 8 * (r >> 2) + 4 * hi;
}
// Fusable DPP add step: s + dpp(s). GCNDPPCombine folds mov_dpp+add -> v_add_f32_dpp.
template <int CTRL>
static __device__ __forceinline__ float dpp_add(float s) {
  int t = __builtin_amdgcn_update_dpp(0, __builtin_bit_cast(int, s), CTRL, 0xf, 0xf, true);
  return s + __builtin_bit_cast(float, t);
}

// ---------------- Kernel 0: weight prep ----------------
// Wq/Wk/Wv f32 [128][2048] -> WT bf16 frag-major: [g=col>>5][ks][hi][il=col&31][8]
// Wo f32 [2048][128] -> WoT bf16 [128 col][2048 k]
__global__ __launch_bounds__(256) void prep_weights(
    const float* __restrict__ Wq, const float* __restrict__ Wk,
    const float* __restrict__ Wv, const float* __restrict__ Wo,
    uint16_t* __restrict__ WqT, uint16_t* __restrict__ WkT,
    uint16_t* __restrict__ WvT, uint16_t* __restrict__ WoT) {
  const int t = threadIdx.x, bx = blockIdx.x, z = blockIdx.y;
  if (z < 3) {
    const float* W = (z == 0) ? Wq : (z == 1) ? Wk : Wv;
    uint16_t* WT = (z == 0) ? WqT : (z == 1) ? WkT : WvT;
    const int col = bx * 256 + t;
    const int g = col >> 5, il = col & 31;
    for (int kc = 0; kc < 16; ++kc) {   // kc = k>>3 : ks = kc>>1, hi = kc&1
      u32x4 wv;
      #pragma unroll
      for (int p = 0; p < 4; ++p) {
        float f0 = W[(size_t)(kc * 8 + 2 * p) * DH + col];
        float f1 = W[(size_t)(kc * 8 + 2 * p + 1) * DH + col];
        wv[p] = cvt_pk_bf16(f0, f1);
      }
      *(u32x4*)(WT + (size_t)g * 4096 + (kc >> 1) * 512 + (kc & 1) * 256 + il * 8) = wv;
    }
  } else {
    const int col = t & 127, ksub = t >> 7;
    const int kbase = bx * 256 + ksub * 128;
    for (int kc = 0; kc < 16; ++kc) {
      const int k0 = kbase + kc * 8;
      u32x4 wv;
      #pragma unroll
      for (int p = 0; p < 4; ++p) {
        float f0 = Wo[(size_t)(k0 + 2 * p) * DDIM + col];
        float f1 = Wo[(size_t)(k0 + 2 * p + 1) * DDIM + col];
        wv[p] = cvt_pk_bf16(f0, f1);
      }
      *(u32x4*)(WoT + (size_t)col * DH + k0) = wv;
    }
  }
}

// ---------------- Kernel 1: Q/K/V projections ----------------
// C = A[8192x128] @ W[128x2048] + b, bf16 out in attention layouts.
// q3/k3 unit: idx = n*2048 + (h>>3)*1024 + i*8 + (h&7)        (f = i*16+h)
// v3   unit: idx = n*2048 + (j>>3)*128 + h*8 + (j&7)          (f = j*16+h)
// q3 is additionally scaled by CEXP = log2(e)/sqrt(128) (folded softmax scale).
__global__ __launch_bounds__(256, 3) void proj_kernel(
    const float* __restrict__ q, const float* __restrict__ kin,
    const float* __restrict__ v,
    const uint16_t* __restrict__ WqT, const uint16_t* __restrict__ WkT,
    const uint16_t* __restrict__ WvT,
    const float* __restrict__ bq, const float* __restrict__ bk,
    const float* __restrict__ bv,
    uint16_t* __restrict__ q3, uint16_t* __restrict__ k3,
    uint16_t* __restrict__ v3) {
  __shared__ uint16_t astage[4096];    // A tile, frag layout [ks][hi][il][8]
  __shared__ uint16_t tile[32 * 512];  // 32 KB destination-layout staging
  const int z = blockIdx.z;
  const float* A = (z == 0) ? q : (z == 1) ? kin : v;
  const uint16_t* WTf = (z == 0) ? WqT : (z == 1) ? WkT : WvT;
  const float* bias = (z == 0) ? bq : (z == 1) ? bk : bv;
  uint16_t* dst = (z == 0) ? q3 : (z == 1) ? k3 : v3;
  const bool vlayout = (z == 2);
  const float CEXP = 1.4426950408889634f * 0.08838834764831845f;
  const float cs = (z == 0) ? CEXP : 1.0f;

  const int t = threadIdx.x;
  const int w = t >> 6, l = t & 63;
  const int il = l & 31, hi = l >> 5;
  const int T = blockIdx.x, by = blockIdx.y;
  const int rowbase = T * 32;

  // ---- stage A tile (32x128 f32 -> bf16 frag layout), coalesced ----
  {
    const int rp = t >> 3, kc = t & 7;
    const float* ap = A + ((size_t)rowbase + rp) * DDIM + kc * 16;
    float4 f0 = *(const float4*)(ap + 0);
    float4 f1 = *(const float4*)(ap + 4);
    float4 f2 = *(const float4*)(ap + 8);
    float4 f3 = *(const float4*)(ap + 12);
    u32x4 u0 = { cvt_pk_bf16(f0.x, f0.y), cvt_pk_bf16(f0.z, f0.w),
                 cvt_pk_bf16(f1.x, f1.y), cvt_pk_bf16(f1.z, f1.w) };
    u32x4 u1 = { cvt_pk_bf16(f2.x, f2.y), cvt_pk_bf16(f2.z, f2.w),
                 cvt_pk_bf16(f3.x, f3.y), cvt_pk_bf16(f3.z, f3.w) };
    *(u32x4*)(astage + kc * 512 + rp * 8) = u0;        // hi=0 half
    *(u32x4*)(astage + kc * 512 + 256 + rp * 8) = u1;  // hi=1 half
  }
  __syncthreads();

  const int lo = hi * 256 + il * 8;
  bf16x8 af[8];
  #pragma unroll
  for (int ks = 0; ks < 8; ++ks)
    af[ks] = *(const bf16x8*)(astage + ks * 512 + lo);

  const uint16_t* WB = WTf + (size_t)(by * 16 + w * 4) * 4096;
  f32x16 acc0 = {}, acc1 = {}, acc2 = {}, acc3 = {};
  #pragma unroll
  for (int ks = 0; ks < 8; ++ks) {
    bf16x8 b0 = *(const bf16x8*)(WB + 0 * 4096 + ks * 512 + lo);
    bf16x8 b1 = *(const bf16x8*)(WB + 1 * 4096 + ks * 512 + lo);
    bf16x8 b2 = *(const bf16x8*)(WB + 2 * 4096 + ks * 512 + lo);
    bf16x8 b3 = *(const bf16x8*)(WB + 3 * 4096 + ks * 512 + lo);
    acc0 = __builtin_amdgcn_mfma_f32_32x32x16_bf16(af[ks], b0, acc0, 0, 0, 0);
    acc1 = __builtin_amdgcn_mfma_f32_32x32x16_bf16(af[ks], b1, acc1, 0, 0, 0);
    acc2 = __builtin_amdgcn_mfma_f32_32x32x16_bf16(af[ks], b2, acc2, 0, 0, 0);
    acc3 = __builtin_amdgcn_mfma_f32_32x32x16_bf16(af[ks], b3, acc3, 0, 0, 0);
  }

  // ---- stage into LDS in destination layout (local col lc) ----
  //   q3/k3: cm = ((lc>>3)&1)*256 + (lc>>4)*8 + (lc&7), XOR-swz bit8->bit4
  //   v3   : cm = ((lc>>7)&3)*128 + (lc&15)*8 + ((lc>>4)&7)   (bank-spread)
  #pragma unroll
  for (int nt = 0; nt < 4; ++nt) {
    const f32x16 acc = (nt == 0) ? acc0 : (nt == 1) ? acc1 : (nt == 2) ? acc2 : acc3;
    const int lc = w * 128 + nt * 32 + il;
    const float bval = bias[by * 512 + lc];
    int cm;
    if (!vlayout) {
      const int c = (lc >> 3) & 1;
      cm = (c * 256 + (lc >> 4) * 8 + (lc & 7)) ^ (c << 4);
    } else {
      cm = ((lc >> 7) & 3) * 128 + (lc & 15) * 8 + ((lc >> 4) & 7);
    }
    #pragma unroll
    for (int r = 0; r < 16; r += 2) {
      const int rr0 = crow4(r, hi);              // r even: rr1 = rr0+1
      const uint32_t pk = cvt_pk_bf16((acc[r] + bval) * cs, (acc[r + 1] + bval) * cs);
      tile[rr0 * 512 + cm] = (uint16_t)pk;
      tile[(rr0 + 1) * 512 + cm] = (uint16_t)(pk >> 16);
    }
  }
  __syncthreads();

  // ---- coalesced store: 2048 16B-units, 8 per thread ----
  #pragma unroll
  for (int kk2 = 0; kk2 < 8; ++kk2) {
    const int u = t + kk2 * 256;
    const int rr = u >> 6, qq = u & 63;
    int toff;
    size_t gaddr;
    const size_t n = rowbase + rr;
    if (!vlayout) {
      toff = (qq * 8) ^ ((qq >> 5) << 4);   // undo stage swizzle
      gaddr = n * 2048 + (size_t)(qq >> 5) * 1024 + (size_t)by * 256 + (qq & 31) * 8;
    } else {
      toff = qq * 8;
      gaddr = n * 2048 + (size_t)by * 512 + (size_t)(qq >> 4) * 128 + (qq & 15) * 8;
    }
    u32x4 val = *(const u32x4*)(tile + rr * 512 + toff);
    *(u32x4*)(dst + gaddr) = val;
  }
}

// ---------------- Kernel 2: per-token attention ----------------
// One WG (4 waves) per token. S^T = k3 · q3^T (softmax over i is a wave-local
// row reduction via DPP), fold 1/denom into P, P->bf16 via cvt_pk +
// permlane32_swap, PV per-mi with immediate LDS partial write (swizzled),
// 4-way cross-wave reduce. out3 overwrites q3 region.
__global__ __launch_bounds__(256) void attn_kernel(
    const uint16_t* q3, const uint16_t* __restrict__ k3,
    const uint16_t* __restrict__ v3, uint16_t* out3) {
  __shared__ float part[4 * 2048];   // [w][h(16)][i(128)], i XOR-swz ((h&7)<<2)
  const int n = blockIdx.x;
  const int w = threadIdx.x >> 6;
  const int l = threadIdx.x & 63;
  const int il = l & 31, hi = l >> 5;
  const uint16_t* qb = q3 + (size_t)n * 2048;
  const uint16_t* kb = k3 + (size_t)n * 2048;
  const uint16_t* vb = v3 + (size_t)n * 2048;

  // A-frag: k3 rows j = 32w+il, k = h = hi*8..+7 ; V B-frags hoisted early.
  bf16x8 af = *(const bf16x8*)(kb + hi * 1024 + (size_t)(w * 32 + il) * 8);
  bf16x8 vf0 = *(const bf16x8*)(vb + (size_t)(w * 4 + hi) * 128 + (il & 15) * 8);
  bf16x8 vf1 = *(const bf16x8*)(vb + (size_t)(w * 4 + hi + 2) * 128 + (il & 15) * 8);
  f32x16 d0 = {}, d1 = {}, d2 = {}, d3 = {};
  {
    bf16x8 bq0 = *(const bf16x8*)(qb + hi * 1024 + (size_t)(0 * 32 + il) * 8);
    bf16x8 bq1 = *(const bf16x8*)(qb + hi * 1024 + (size_t)(1 * 32 + il) * 8);
    bf16x8 bq2 = *(const bf16x8*)(qb + hi * 1024 + (size_t)(2 * 32 + il) * 8);
    bf16x8 bq3 = *(const bf16x8*)(qb + hi * 1024 + (size_t)(3 * 32 + il) * 8);
    d0 = __builtin_amdgcn_mfma_f32_32x32x16_bf16(af, bq0, d0, 0, 0, 0);
    d1 = __builtin_amdgcn_mfma_f32_32x32x16_bf16(af, bq1, d1, 0, 0, 0);
    d2 = __builtin_amdgcn_mfma_f32_32x32x16_bf16(af, bq2, d2, 0, 0, 0);
    d3 = __builtin_amdgcn_mfma_f32_32x32x16_bf16(af, bq3, d3, 0, 0, 0);
  }
  // softmax over i (cols); scale already folded into q3. Per row (reg,hi):
  // sum 4 tiles + DPP reduce (quad xor1, xor2, row_ror4, row_ror8) + xor16.
  #pragma unroll
  for (int r = 0; r < 16; ++r) {
    float e0 = exp2f(d0[r]), e1 = exp2f(d1[r]);
    float e2 = exp2f(d2[r]), e3 = exp2f(d3[r]);
    float s = (e0 + e1) + (e2 + e3);
    s = dpp_add<0xB1>(s);    // quad_perm [1,0,3,2]  (xor 1)
    s = dpp_add<0x4E>(s);    // quad_perm [2,3,0,1]  (xor 2)
    s = dpp_add<0x124>(s);   // row_ror:4
    s = dpp_add<0x128>(s);   // row_ror:8  -> 16-lane row sum in all lanes
    s += __shfl_xor(s, 16);  // cross 16 within 32
    const float rs = __builtin_amdgcn_rcpf(s);
    d0[r] = e0 * rs; d1[r] = e1 * rs; d2[r] = e2 * rs; d3[r] = e3 * rs;
  }
  // PV per i-tile: pack P^T -> A-frags, 2 MFMA, immediate partial write to LDS.
  #pragma unroll
  for (int mi = 0; mi < 4; ++mi) {
    const f32x16 p = (mi == 0) ? d0 : (mi == 1) ? d1 : (mi == 2) ? d2 : d3;
    uint32_t pk0 = cvt_pk_bf16(p[0],  p[1]),  pk1 = cvt_pk_bf16(p[2],  p[3]);
    uint32_t pk2 = cvt_pk_bf16(p[4],  p[5]),  pk3 = cvt_pk_bf16(p[6],  p[7]);
    uint32_t pk4 = cvt_pk_bf16(p[8],  p[9]),  pk5 = cvt_pk_bf16(p[10], p[11]);
    uint32_t pk6 = cvt_pk_bf16(p[12], p[13]), pk7 = cvt_pk_bf16(p[14], p[15]);
    // swap(x,y): r[0] = [x_lo | y_lo], r[1] = [x_hi | y_hi]
    auto sA = __builtin_amdgcn_permlane32_swap(pk0, pk2, false, false); // W0, W2
    auto sB = __builtin_amdgcn_permlane32_swap(pk1, pk3, false, false); // W1, W3
    auto sC = __builtin_amdgcn_permlane32_swap(pk4, pk6, false, false); // W0',W2'
    auto sD = __builtin_amdgcn_permlane32_swap(pk5, pk7, false, false); // W1',W3'
    u32x4 fw0 = { sA[0], sB[0], sA[1], sB[1] };
    u32x4 fw1 = { sC[0], sD[0], sC[1], sD[1] };
    f32x16 oz = {};
    oz = __builtin_amdgcn_mfma_f32_32x32x16_bf16(__builtin_bit_cast(bf16x8, fw0), vf0, oz, 0, 0, 0);
    oz = __builtin_amdgcn_mfma_f32_32x32x16_bf16(__builtin_bit_cast(bf16x8, fw1), vf1, oz, 0, 0, 0);
    if (il < 16) {
      #pragma unroll
      for (int r = 0; r < 16; r += 2) {
        const int i = mi * 32 + crow4(r, hi);    // even; pair (i, i+1)
        float2 val = { oz[r], oz[r + 1] };
        *(float2*)&part[w * 2048 + il * 128 + (i ^ ((il & 7) << 2))] = val;
      }
    }
  }
  __syncthreads();
  const int t = threadIdx.x;
  const int i0 = t >> 1, h0 = (t & 1) * 8;
  float sv[8];
  #pragma unroll
  for (int e = 0; e < 8; ++e) {
    const int idx = (h0 + e) * 128 + (i0 ^ (((h0 + e) & 7) << 2));
    sv[e] = (part[idx] + part[2048 + idx]) + (part[4096 + idx] + part[6144 + idx]);
  }
  u32x4 ov = { cvt_pk_bf16(sv[0], sv[1]), cvt_pk_bf16(sv[2], sv[3]),
               cvt_pk_bf16(sv[4], sv[5]), cvt_pk_bf16(sv[6], sv[7]) };
  *(u32x4*)(out3 + (size_t)n * 2048 + t * 8) = ov;
}

// ---------------- Kernel 3: output projection ----------------
// out = out3[8192x2048](bf16) @ Wo + bo, f32 out. K-split 2 per block.
__global__ __launch_bounds__(512) void outproj_kernel(
    const uint16_t* __restrict__ out3, const uint16_t* __restrict__ WoT,
    const float* __restrict__ bo, float* __restrict__ out) {
  __shared__ float part[4][32][32];
  const int w = threadIdx.x >> 6;
  const int l = threadIdx.x & 63;
  const int il = l & 31, hi = l >> 5;
  const int nt = w >> 1, ksv = w & 1;
  const int rowbase = blockIdx.x * 32;
  f32x16 acc = {};
  #pragma unroll 4
  for (int kb = 0; kb < 64; ++kb) {
    const int kk = ksv * 1024 + kb * 16 + hi * 8;
    bf16x8 afr = *(const bf16x8*)(out3 + (size_t)(rowbase + il) * DH + kk);
    bf16x8 bfr = *(const bf16x8*)(WoT + (size_t)(nt * 32 + il) * DH + kk);
    acc = __builtin_amdgcn_mfma_f32_32x32x16_bf16(afr, bfr, acc, 0, 0, 0);
  }
  if (ksv == 1) {
    #pragma unroll
    for (int r = 0; r < 16; ++r) part[nt][crow4(r, hi)][il] = acc[r];
  }
  __syncthreads();
  if (ksv == 0) {
    const int col = nt * 32 + il;
    const float bval = bo[col];
    #pragma unroll
    for (int r = 0; r < 16; ++r) {
      const int rr = crow4(r, hi);
      out[(size_t)(rowbase + rr) * DDIM + col] = acc[r] + part[nt][rr][il] + bval;
    }
  }
}

extern "C" void kernel_launch(void* const* d_in, const int* in_sizes, int n_in,
                              void* d_out, int out_size, void* d_ws, size_t ws_size,
                              hipStream_t stream) {
  (void)in_sizes; (void)n_in; (void)out_size; (void)ws_size;
  const float* q  = (const float*)d_in[0];
  const float* k  = (const float*)d_in[1];
  const float* v  = (const float*)d_in[2];
  const float* Wq = (const float*)d_in[3];
  const float* bq = (const float*)d_in[4];
  const float* Wk = (const float*)d_in[5];
  const float* bk = (const float*)d_in[6];
  const float* Wv = (const float*)d_in[7];
  const float* bv = (const float*)d_in[8];
  const float* Wo = (const float*)d_in[9];
  const float* bo = (const float*)d_in[10];
  float* out = (float*)d_out;

  char* ws = (char*)d_ws;
  const size_t MB = 1024ull * 1024ull;
  uint16_t* q3  = (uint16_t*)(ws);             // 32MB; becomes out3
  uint16_t* k3  = (uint16_t*)(ws + 32 * MB);
  uint16_t* v3  = (uint16_t*)(ws + 64 * MB);
  uint16_t* WqT = (uint16_t*)(ws + 96 * MB);   // 512KB each
  uint16_t* WkT = WqT + (size_t)DH * 128;
  uint16_t* WvT = WkT + (size_t)DH * 128;
  uint16_t* WoT = WvT + (size_t)DH * 128;

  prep_weights<<<dim3(8, 4), 256, 0, stream>>>(Wq, Wk, Wv, Wo, WqT, WkT, WvT, WoT);
  proj_kernel<<<dim3(256, 4, 3), 256, 0, stream>>>(q, k, v, WqT, WkT, WvT,
                                                   bq, bk, bv, q3, k3, v3);
  attn_kernel<<<dim3(NTOK), 256, 0, stream>>>(q3, k3, v3, q3);
  outproj_kernel<<<dim3(256), 512, 0, stream>>>(q3, WoT, bo, out);
}